// Round 3
// baseline (425.897 us; speedup 1.0000x reference)
//
#include <hip/hip_runtime.h>

// ---------------------------------------------------------------------------
// AttentionHead: B=4, C=256, N=4096, QK=64. Column-softmax attention.
// R15: R14's zero-LDS k_attn (verified-correct swapped QK^T + permlane pack)
// with the latency exposure fixed:
//  - j-split: block = 8 waves = 4 i-subtiles x 2 j-halves (each wave sweeps
//    2048 j); one-time 32KB LDS combine. 4096 waves -> 4 waves/SIMD (R14 had
//    2048 -> 2/SIMD, Occ 23%, per-iter slot 2285cy vs ~300cy issue cost).
//  - non-volatile cvt_pk / permlane32_swap asm (R14's 24 volatile ops/iter
//    pinned the scheduler).
//  - S-MFMA split into 2 independent 2-deep chains; K frags for iter+1
//    prefetched during exp/pack; V loads issued at iter top.
//  - __launch_bounds__(512,4) caps VGPR at 128 (occupancy cliff guard).
// Other kernels = R12/R14 (k_colsum folds 1/colsum into Vc in place).
// Workspace: 29,884,416 bytes (rs slot unused).
// ---------------------------------------------------------------------------

typedef unsigned short u16;
typedef __attribute__((ext_vector_type(8))) unsigned short ushort8;
typedef __attribute__((ext_vector_type(8))) __bf16 bf16x8;
typedef __attribute__((ext_vector_type(4))) float f32x4;
typedef __attribute__((ext_vector_type(16))) float f32x16;
typedef __attribute__((ext_vector_type(4))) unsigned int uint4v;

#define MFMA16(a, b, c) __builtin_amdgcn_mfma_f32_16x16x32_bf16((a), (b), (c), 0, 0, 0)
#define MFMA32(a, b, c) __builtin_amdgcn_mfma_f32_32x32x16_bf16((a), (b), (c), 0, 0, 0)

// v_permlane32_swap_b32: a.hi32lanes <-> b.lo32lanes (both updated).
// Non-volatile: dataflow fully expressed via "+v", scheduler may move it.
#define PLSWAP(a, b) asm("v_permlane32_swap_b32 %0, %1" : "+v"(a), "+v"(b))

__device__ __forceinline__ u16 f2bf(float f) {
  unsigned int u = __builtin_bit_cast(unsigned int, f);
  u += 0x7FFFu + ((u >> 16) & 1u);  // round-to-nearest-even
  return (u16)(u >> 16);
}

__device__ __forceinline__ float bf2f(u16 v) {
  return __builtin_bit_cast(float, (unsigned int)v << 16);
}

__device__ __forceinline__ unsigned int cvtpk(float lo, float hi) {
  unsigned int r;
  asm("v_cvt_pk_bf16_f32 %0, %1, %2" : "=v"(r) : "v"(lo), "v"(hi));
  return r;
}

__device__ __forceinline__ bf16x8 mk8(unsigned int w0, unsigned int w1,
                                      unsigned int w2, unsigned int w3) {
  uint4v u = {w0, w1, w2, w3};
  return __builtin_bit_cast(bf16x8, u);
}

__device__ __forceinline__ bf16x8 ld8(const u16* p) {
  return __builtin_bit_cast(bf16x8, *reinterpret_cast<const ushort8*>(p));
}

__device__ __forceinline__ f32x4 fz4() {
  f32x4 z = {0.f, 0.f, 0.f, 0.f};
  return z;
}

__device__ __forceinline__ f32x16 fz16() {
  f32x16 z = {0.f, 0.f, 0.f, 0.f, 0.f, 0.f, 0.f, 0.f,
              0.f, 0.f, 0.f, 0.f, 0.f, 0.f, 0.f, 0.f};
  return z;
}

// ---- convert all weight matrices fp32 -> bf16 (one launch) ----------------
__global__ __launch_bounds__(256) void k_convert(
    const float* __restrict__ wq, const float* __restrict__ wk,
    const float* __restrict__ wv, const float* __restrict__ w1,
    const float* __restrict__ w2, u16* __restrict__ dq, u16* __restrict__ dk,
    u16* __restrict__ dv, u16* __restrict__ d1, u16* __restrict__ d2) {
  int i = blockIdx.x * 256 + threadIdx.x;
  if (i < 16384)       dq[i]           = f2bf(wq[i]);
  else if (i < 32768)  dk[i - 16384]   = f2bf(wk[i - 16384]);
  else if (i < 98304)  dv[i - 32768]   = f2bf(wv[i - 32768]);
  else if (i < 163840) d1[i - 98304]   = f2bf(w1[i - 98304]);
  else                 d2[i - 163840]  = f2bf(w2[i - 163840]);
}

// ---- x [b][256][4096] fp32 -> xT [b][4096][256] bf16 (LDS-tiled) ----------
__global__ __launch_bounds__(256) void k_transpose(const float* __restrict__ x,
                                                   u16* __restrict__ xT) {
  __shared__ float t[64][65];
  int n0 = blockIdx.x * 64, c0 = blockIdx.y * 64, b = blockIdx.z;
  int tx = threadIdx.x & 63, ty = threadIdx.x >> 6;
  const float* xb = x + ((size_t)b * 256 + c0) * 4096 + n0;
#pragma unroll
  for (int i = 0; i < 64; i += 4) t[ty + i][tx] = xb[(size_t)(ty + i) * 4096 + tx];
  __syncthreads();
  u16* xo = xT + ((size_t)b * 4096 + n0) * 256 + c0;
#pragma unroll
  for (int i = 0; i < 64; i += 4) xo[(size_t)(ty + i) * 256 + tx] = f2bf(t[tx][ty + i]);
}

// ---- fused QKV projection: 32-pos tiles, grid 512 linear (b = id&3) -------
__global__ __launch_bounds__(256) void k_proj(
    const u16* __restrict__ xT, const u16* __restrict__ wq,
    const u16* __restrict__ wk, const u16* __restrict__ wv,
    const float* __restrict__ bQ, const float* __restrict__ bK,
    const float* __restrict__ bV, const float* __restrict__ PE,
    u16* __restrict__ Qt, u16* __restrict__ Kt, u16* __restrict__ Vc) {
  int b = blockIdx.x & 3, n0 = (blockIdx.x >> 2) * 32;
  int lane = threadIdx.x & 63, wid = threadIdx.x >> 6;
  int l15 = lane & 15, g = lane >> 4;
  const u16* xrow = xT + ((size_t)b * 4096 + n0) * 256;

  f32x4 aq[2], ak[2], av[4][2];
#pragma unroll
  for (int m = 0; m < 2; ++m) { aq[m] = fz4(); ak[m] = fz4(); }
#pragma unroll
  for (int m = 0; m < 4; ++m)
#pragma unroll
    for (int n = 0; n < 2; ++n) av[m][n] = fz4();

  for (int kk = 0; kk < 8; ++kk) {
    int ko = kk * 32 + g * 8;
    bf16x8 xa[2];
#pragma unroll
    for (int m = 0; m < 2; ++m) xa[m] = ld8(xrow + (16 * m + l15) * 256 + ko);
    bf16x8 fq = ld8(wq + (16 * wid + l15) * 256 + ko);
    bf16x8 fk = ld8(wk + (16 * wid + l15) * 256 + ko);
#pragma unroll
    for (int m = 0; m < 2; ++m) {
      aq[m] = MFMA16(xa[m], fq, aq[m]);
      ak[m] = MFMA16(xa[m], fk, ak[m]);
    }
    bf16x8 fv[4];
#pragma unroll
    for (int m = 0; m < 4; ++m) fv[m] = ld8(wv + (64 * wid + 16 * m + l15) * 256 + ko);
#pragma unroll
    for (int m = 0; m < 4; ++m)
#pragma unroll
      for (int n = 0; n < 2; ++n) av[m][n] = MFMA16(fv[m], xa[n], av[m][n]);
  }

  int o = 16 * wid + l15;
#pragma unroll
  for (int m = 0; m < 2; ++m)
#pragma unroll
    for (int r = 0; r < 4; ++r) {
      int pos = n0 + 16 * m + 4 * g + r;
      float pe = PE[o * 4096 + pos];
      Qt[((size_t)b * 4096 + pos) * 64 + o] = f2bf(aq[m][r] + bQ[o] + pe);
      Kt[((size_t)b * 4096 + pos) * 64 + o] = f2bf(ak[m][r] + bK[o] + pe);
    }
#pragma unroll
  for (int m = 0; m < 4; ++m) {
    int ov = 64 * wid + 16 * m + 4 * g;
#pragma unroll
    for (int r = 0; r < 4; ++r) {
      float bvv = bV[ov + r];
#pragma unroll
      for (int n = 0; n < 2; ++n) {
        int pos = n0 + 16 * n + l15;
        Vc[((size_t)b * 256 + ov + r) * 4096 + pos] = f2bf(av[m][n][r] + bvv);
      }
    }
  }
}

// ---- pass 1: column sums + fold 1/colsum into V, 512 thr, grid 256 --------
__global__ __launch_bounds__(512) void k_colsum(const u16* __restrict__ Qt,
                                                const u16* __restrict__ Kt,
                                                u16* __restrict__ Vc) {
  __shared__ float ps[8][16];
  __shared__ float rsf[64];
  int b = blockIdx.x & 3, j0 = (blockIdx.x >> 2) * 64;
  int lane = threadIdx.x & 63, wid = threadIdx.x >> 6;  // wid in [0,8)
  int l15 = lane & 15, g = lane >> 4;
  int w4 = wid & 3, ihalf = wid >> 2;
  const u16* qb = Qt + (size_t)b * 262144;
  const u16* kb = Kt + (size_t)b * 262144;
  int j = j0 + 16 * w4 + l15;
  bf16x8 fk[2];
#pragma unroll
  for (int h = 0; h < 2; ++h) fk[h] = ld8(kb + j * 64 + h * 32 + 8 * g);
  float part = 0.f;
  for (int i0 = ihalf * 2048; i0 < ihalf * 2048 + 2048; i0 += 64) {
    f32x4 acc[4];
#pragma unroll
    for (int m = 0; m < 4; ++m) acc[m] = fz4();
#pragma unroll
    for (int m = 0; m < 4; ++m) {
      const u16* qr = qb + (i0 + 16 * m + l15) * 64;
      acc[m] = MFMA16(ld8(qr + 8 * g), fk[0], acc[m]);
      acc[m] = MFMA16(ld8(qr + 32 + 8 * g), fk[1], acc[m]);
    }
#pragma unroll
    for (int m = 0; m < 4; ++m)
#pragma unroll
      for (int r = 0; r < 4; ++r) part += __expf(acc[m][r] * 0.125f);
  }
  part += __shfl_xor(part, 16);
  part += __shfl_xor(part, 32);
  if (g == 0) ps[wid][l15] = part;
  __syncthreads();
  if (threadIdx.x < 64) {
    int jj = threadIdx.x;
    rsf[jj] = 1.0f / (ps[jj >> 4][jj & 15] + ps[(jj >> 4) + 4][jj & 15]);
  }
  __syncthreads();
  // scale V columns j0..j0+63 across all 256 channels (2 threads / channel)
  {
    int c = threadIdx.x >> 1, half = threadIdx.x & 1;
    u16* vp = Vc + ((size_t)b * 256 + c) * 4096 + j0 + half * 32;
#pragma unroll
    for (int q = 0; q < 4; ++q) {
      ushort8 v = *reinterpret_cast<const ushort8*>(vp + q * 8);
      ushort8 ov;
#pragma unroll
      for (int e = 0; e < 8; ++e)
        ov[e] = f2bf(bf2f(v[e]) * rsf[half * 32 + q * 8 + e]);
      *reinterpret_cast<ushort8*>(vp + q * 8) = ov;
    }
  }
}

// ---- pass 2: attention, 512 thr, grid 512, j-split + one LDS combine ------
// Block: 128i x 64c. Wave (wid&3)=i-subtile (32 i), (wid>>2)=j-half (2048 j).
// Per 32-j step: S^T = K_j . Q_i^T (2 indep 2-deep MFMA32 chains), exp,
// cvt_pk+permlane32_swap -> PV A-frags in-register, 4 PV MFMA32.
// rs pre-folded into Vc. K frags for step+1 prefetched during exp/pack.
__global__ __launch_bounds__(512, 4) void k_attn(
    const u16* __restrict__ Qt, const u16* __restrict__ Kt,
    const u16* __restrict__ Vc, u16* __restrict__ attT) {
  __shared__ float Ls[4][2][16][64];  // 32 KB: [i-subtile][ctile][reg][lane]
  int id = blockIdx.x;
  int b = id & 3;
  int r2 = id >> 2;                  // 0..127
  int ib = r2 & 31, cb = r2 >> 5;    // same-XCD neighbors share cb (V stream)
  int i0 = ib * 128, c0 = cb * 64;
  int lane = threadIdx.x & 63, wid = threadIdx.x >> 6;  // wid in [0,8)
  int w4 = wid & 3, jh = wid >> 2;
  int l31 = lane & 31, hi = lane >> 5;
  int iw = i0 + w4 * 32;

  const u16* qb = Qt + (size_t)b * 262144;
  const u16* kb = Kt + (size_t)b * 262144;
  const u16* vb = Vc + (size_t)b * 1048576;

  // Q B-fragments for this wave's 32 i rows (held for entire j sweep)
  bf16x8 aq[4];
#pragma unroll
  for (int dc = 0; dc < 4; ++dc)
    aq[dc] = ld8(qb + (iw + l31) * 64 + dc * 16 + hi * 8);

  f32x16 o0 = fz16(), o1 = fz16();  // out tiles: c0+l31 / c0+32+l31

  const u16* krow = kb + (size_t)(jh * 2048 + l31) * 64 + hi * 8;
  const u16* v0 = vb + (size_t)(c0 + l31) * 4096 + jh * 2048 + hi * 8;
  const u16* v1 = v0 + (size_t)32 * 4096;

  bf16x8 ka0 = ld8(krow), ka1 = ld8(krow + 16);
  bf16x8 ka2 = ld8(krow + 32), ka3 = ld8(krow + 48);

#pragma unroll 1
  for (int it = 0; it < 64; ++it) {
    int jo = it * 32;
    // V loads for this step (consumed at the end -> ~full step of latency)
    bf16x8 fva0 = ld8(v0 + jo);
    bf16x8 fvb0 = ld8(v1 + jo);
    bf16x8 fva1 = ld8(v0 + jo + 16);
    bf16x8 fvb1 = ld8(v1 + jo + 16);

    // S^T[j][i] 32x32, d=64: two independent 2-deep chains
    f32x16 sa = MFMA32(ka0, aq[0], fz16());
    f32x16 sb = MFMA32(ka1, aq[1], fz16());
    sa = MFMA32(ka2, aq[2], sa);
    sb = MFMA32(ka3, aq[3], sb);

    // prefetch next step's K fragments (latency hides under exp/pack)
    if (it < 63) {
      const u16* kn = krow + (size_t)(jo + 32) * 64;
      ka0 = ld8(kn);
      ka1 = ld8(kn + 16);
      ka2 = ld8(kn + 32);
      ka3 = ld8(kn + 48);
    }

    float s[16];
#pragma unroll
    for (int r = 0; r < 16; ++r) s[r] = __expf((sa[r] + sb[r]) * 0.125f);

    // chunk0 (j 0..15): lane needs j = 8*hi + e
    unsigned int a0 = cvtpk(s[0], s[1]), a1 = cvtpk(s[2], s[3]);
    unsigned int b0 = cvtpk(s[4], s[5]), b1 = cvtpk(s[6], s[7]);
    PLSWAP(a0, b0);
    PLSWAP(a1, b1);
    bf16x8 pa0 = mk8(a0, a1, b0, b1);
    // chunk1 (j 16..31)
    unsigned int e0 = cvtpk(s[8], s[9]), e1 = cvtpk(s[10], s[11]);
    unsigned int f0 = cvtpk(s[12], s[13]), f1 = cvtpk(s[14], s[15]);
    PLSWAP(e0, f0);
    PLSWAP(e1, f1);
    bf16x8 pa1 = mk8(e0, e1, f0, f1);

    o0 = MFMA32(pa0, fva0, o0);
    o1 = MFMA32(pa0, fvb0, o1);
    o0 = MFMA32(pa1, fva1, o0);
    o1 = MFMA32(pa1, fvb1, o1);
  }

  // combine j-halves: jh=1 waves publish partials, jh=0 waves add + store
  if (jh == 1) {
#pragma unroll
    for (int r = 0; r < 16; ++r) {
      Ls[w4][0][r][lane] = o0[r];
      Ls[w4][1][r][lane] = o1[r];
    }
  }
  __syncthreads();
  if (jh == 0) {
#pragma unroll
    for (int r = 0; r < 16; ++r) {
      float t0 = o0[r] + Ls[w4][0][r][lane];
      float t1 = o1[r] + Ls[w4][1][r][lane];
      int i = iw + (r & 3) + 8 * (r >> 2) + 4 * hi;
      size_t base = ((size_t)b * 4096 + i) * 256;
      attT[base + c0 + l31] = f2bf(t0);
      attT[base + c0 + 32 + l31] = f2bf(t1);
    }
  }
}

// ---- fused MLP, 512 thr, grid 256 linear (b = id&3) -----------------------
__global__ __launch_bounds__(512) void k_mlp(
    const u16* __restrict__ attT, const u16* __restrict__ w1,
    const float* __restrict__ b1, const u16* __restrict__ w2,
    const float* __restrict__ b2, const float* __restrict__ x,
    float* __restrict__ out) {
  __shared__ u16 hdnS[64][264];
  int b = blockIdx.x & 3, n0 = (blockIdx.x >> 2) * 64;
  int lane = threadIdx.x & 63, wid = threadIdx.x >> 6;  // wid in [0,8)
  int l15 = lane & 15, g = lane >> 4;
  const u16* arow = attT + ((size_t)b * 4096 + n0) * 256;

  // stage 1: hdn = mish(att @ W1^T + b1) -> LDS; wave strip = 32 h-channels
  {
    f32x4 acc[4][2];
#pragma unroll
    for (int m = 0; m < 4; ++m)
#pragma unroll
      for (int n = 0; n < 2; ++n) acc[m][n] = fz4();
    for (int kk = 0; kk < 8; ++kk) {
      int ko = kk * 32 + 8 * g;
      bf16x8 am[4], bn[2];
#pragma unroll
      for (int m = 0; m < 4; ++m) am[m] = ld8(arow + (16 * m + l15) * 256 + ko);
#pragma unroll
      for (int n = 0; n < 2; ++n) bn[n] = ld8(w1 + (32 * wid + 16 * n + l15) * 256 + ko);
#pragma unroll
      for (int m = 0; m < 4; ++m)
#pragma unroll
        for (int n = 0; n < 2; ++n) acc[m][n] = MFMA16(am[m], bn[n], acc[m][n]);
    }
#pragma unroll
    for (int m = 0; m < 4; ++m)
#pragma unroll
      for (int n = 0; n < 2; ++n) {
        int hh = 32 * wid + 16 * n + l15;
        float bb = b1[hh];
#pragma unroll
        for (int r = 0; r < 4; ++r) {
          float v = acc[m][n][r] + bb;
          float sp = (v > 15.f) ? v : __logf(1.f + __expf(v));
          float e2 = __expf(-2.f * sp);
          float th = (1.f - e2) / (1.f + e2);
          hdnS[16 * m + 4 * g + r][hh] = f2bf(v * th);
        }
      }
  }
  __syncthreads();

  // stage 2: out = hdn @ W2^T + b2 + x; wave strip = 32 o-channels
  {
    f32x4 acc[2][4];
#pragma unroll
    for (int m = 0; m < 2; ++m)
#pragma unroll
      for (int n = 0; n < 4; ++n) acc[m][n] = fz4();
    for (int kk = 0; kk < 8; ++kk) {
      int ko = kk * 32 + 8 * g;
      bf16x8 am[2], bn[4];
#pragma unroll
      for (int m = 0; m < 2; ++m) am[m] = ld8(w2 + (32 * wid + 16 * m + l15) * 256 + ko);
#pragma unroll
      for (int n = 0; n < 4; ++n) bn[n] = ld8(&hdnS[16 * n + l15][ko]);
#pragma unroll
      for (int m = 0; m < 2; ++m)
#pragma unroll
        for (int n = 0; n < 4; ++n) acc[m][n] = MFMA16(am[m], bn[n], acc[m][n]);
    }
#pragma unroll
    for (int m = 0; m < 2; ++m)
#pragma unroll
      for (int r = 0; r < 4; ++r) {
        int o = 32 * wid + 16 * m + 4 * g + r;
        float bias = b2[o];
#pragma unroll
        for (int n = 0; n < 4; ++n) {
          int pos = n0 + 16 * n + l15;
          size_t idx = ((size_t)b * 256 + o) * 4096 + pos;
          out[idx] = acc[m][n][r] + bias + x[idx];
        }
      }
  }
}

// ---- workspace layout (bytes) ---------------------------------------------
#define WS_XT 0u          //  8,388,608  xT  [4][4096][256] bf16
#define WS_QT 8388608u    //  2,097,152  Qt  [4][4096][64]  bf16
#define WS_KT 10485760u   //  2,097,152  Kt  [4][4096][64]  bf16
#define WS_VC 12582912u   //  8,388,608  Vc  [4][256][4096] bf16
#define WS_ATT 20971520u  //  8,388,608  attT[4][4096][256] bf16
#define WS_RS 29360128u   //     65,536  (unused since R14)
#define WS_WQ 29425664u   //     32,768
#define WS_WK 29458432u   //     32,768
#define WS_WV 29491200u   //    131,072
#define WS_W1 29622272u   //    131,072
#define WS_W2 29753344u   //    131,072   (end: 29,884,416)

extern "C" void kernel_launch(void* const* d_in, const int* in_sizes, int n_in,
                              void* d_out, int out_size, void* d_ws, size_t ws_size,
                              hipStream_t stream) {
  (void)in_sizes; (void)n_in; (void)out_size; (void)ws_size;
  const float* x  = (const float*)d_in[0];
  const float* WQ = (const float*)d_in[1];
  const float* bQ = (const float*)d_in[2];
  const float* WK = (const float*)d_in[3];
  const float* bK = (const float*)d_in[4];
  const float* WV = (const float*)d_in[5];
  const float* bV = (const float*)d_in[6];
  const float* PE = (const float*)d_in[7];
  const float* W1 = (const float*)d_in[8];
  const float* b1 = (const float*)d_in[9];
  const float* W2 = (const float*)d_in[10];
  const float* b2 = (const float*)d_in[11];
  float* out = (float*)d_out;
  char* ws = (char*)d_ws;

  u16* xT   = (u16*)(ws + WS_XT);
  u16* Qt   = (u16*)(ws + WS_QT);
  u16* Kt   = (u16*)(ws + WS_KT);
  u16* Vc   = (u16*)(ws + WS_VC);
  u16* attT = (u16*)(ws + WS_ATT);
  u16* wqB  = (u16*)(ws + WS_WQ);
  u16* wkB  = (u16*)(ws + WS_WK);
  u16* wvB  = (u16*)(ws + WS_WV);
  u16* w1B  = (u16*)(ws + WS_W1);
  u16* w2B  = (u16*)(ws + WS_W2);

  k_convert<<<896, 256, 0, stream>>>(WQ, WK, WV, W1, W2, wqB, wkB, wvB, w1B, w2B);
  k_transpose<<<dim3(64, 4, 4), 256, 0, stream>>>(x, xT);
  k_proj<<<512, 256, 0, stream>>>(xT, wqB, wkB, wvB, bQ, bK, bV, PE, Qt, Kt, Vc);
  k_colsum<<<256, 512, 0, stream>>>(Qt, Kt, Vc);
  k_attn<<<512, 512, 0, stream>>>(Qt, Kt, Vc, attT);
  k_mlp<<<256, 512, 0, stream>>>(attT, w1B, b1, w2B, b2, x, out);
}

// Round 4
// 343.679 us; speedup vs baseline: 1.2392x; 1.2392x over previous
//
#include <hip/hip_runtime.h>

// ---------------------------------------------------------------------------
// AttentionHead: B=4, C=256, N=4096, QK=64. Column-softmax attention.
// R16 = R12 (the 284.8us best) with ONE change: k_attn occupancy 16->32
// waves/CU. i-block 64->32 rows, grid 256->512 (b=id&3 XCD pin kept),
// block stays 1024 thr; P tile 32x264 u16 (16.9KB) so 2 blocks/CU fit;
// __launch_bounds__(1024,8) caps VGPR at 64 for 8 waves/SIMD.
// Rationale: R12 k_attn is latency-bound (MfmaUtil 16, VALU 17, HBM 2%,
// Occ 43, LDS-BW floor only ~27us of 107us); R13 failed because 2x8-wave
// blocks = same 16 waves/CU (no occupancy gain). R14/R15 zero-LDS rewrites
// failed (L1-serialized private K streams). Inner loop here is R12 verbatim
// with m-loop 4->2. All other kernels byte-identical to R12.
// Workspace: 29,884,416 bytes.
// ---------------------------------------------------------------------------

typedef unsigned short u16;
typedef __attribute__((ext_vector_type(8))) unsigned short ushort8;
typedef __attribute__((ext_vector_type(8))) __bf16 bf16x8;
typedef __attribute__((ext_vector_type(4))) float f32x4;

#define MFMA16(a, b, c) __builtin_amdgcn_mfma_f32_16x16x32_bf16((a), (b), (c), 0, 0, 0)

__device__ __forceinline__ u16 f2bf(float f) {
  unsigned int u = __builtin_bit_cast(unsigned int, f);
  u += 0x7FFFu + ((u >> 16) & 1u);  // round-to-nearest-even
  return (u16)(u >> 16);
}

__device__ __forceinline__ bf16x8 ld8(const u16* p) {
  return __builtin_bit_cast(bf16x8, *reinterpret_cast<const ushort8*>(p));
}

__device__ __forceinline__ f32x4 fz4() {
  f32x4 z = {0.f, 0.f, 0.f, 0.f};
  return z;
}

// ---- convert all weight matrices fp32 -> bf16 (one launch) ----------------
__global__ __launch_bounds__(256) void k_convert(
    const float* __restrict__ wq, const float* __restrict__ wk,
    const float* __restrict__ wv, const float* __restrict__ w1,
    const float* __restrict__ w2, u16* __restrict__ dq, u16* __restrict__ dk,
    u16* __restrict__ dv, u16* __restrict__ d1, u16* __restrict__ d2) {
  int i = blockIdx.x * 256 + threadIdx.x;
  if (i < 16384)       dq[i]           = f2bf(wq[i]);
  else if (i < 32768)  dk[i - 16384]   = f2bf(wk[i - 16384]);
  else if (i < 98304)  dv[i - 32768]   = f2bf(wv[i - 32768]);
  else if (i < 163840) d1[i - 98304]   = f2bf(w1[i - 98304]);
  else                 d2[i - 163840]  = f2bf(w2[i - 163840]);
}

// ---- x [b][256][4096] fp32 -> xT [b][4096][256] bf16 (LDS-tiled) ----------
__global__ __launch_bounds__(256) void k_transpose(const float* __restrict__ x,
                                                   u16* __restrict__ xT) {
  __shared__ float t[64][65];
  int n0 = blockIdx.x * 64, c0 = blockIdx.y * 64, b = blockIdx.z;
  int tx = threadIdx.x & 63, ty = threadIdx.x >> 6;
  const float* xb = x + ((size_t)b * 256 + c0) * 4096 + n0;
#pragma unroll
  for (int i = 0; i < 64; i += 4) t[ty + i][tx] = xb[(size_t)(ty + i) * 4096 + tx];
  __syncthreads();
  u16* xo = xT + ((size_t)b * 4096 + n0) * 256 + c0;
#pragma unroll
  for (int i = 0; i < 64; i += 4) xo[(size_t)(ty + i) * 256 + tx] = f2bf(t[tx][ty + i]);
}

// ---- fused QKV projection: 32-pos tiles, grid 512 linear (b = id&3) -------
__global__ __launch_bounds__(256) void k_proj(
    const u16* __restrict__ xT, const u16* __restrict__ wq,
    const u16* __restrict__ wk, const u16* __restrict__ wv,
    const float* __restrict__ bQ, const float* __restrict__ bK,
    const float* __restrict__ bV, const float* __restrict__ PE,
    u16* __restrict__ Qt, u16* __restrict__ Kt, u16* __restrict__ Vc) {
  int b = blockIdx.x & 3, n0 = (blockIdx.x >> 2) * 32;
  int lane = threadIdx.x & 63, wid = threadIdx.x >> 6;
  int l15 = lane & 15, g = lane >> 4;
  const u16* xrow = xT + ((size_t)b * 4096 + n0) * 256;

  f32x4 aq[2], ak[2], av[4][2];
#pragma unroll
  for (int m = 0; m < 2; ++m) { aq[m] = fz4(); ak[m] = fz4(); }
#pragma unroll
  for (int m = 0; m < 4; ++m)
#pragma unroll
    for (int n = 0; n < 2; ++n) av[m][n] = fz4();

  for (int kk = 0; kk < 8; ++kk) {
    int ko = kk * 32 + g * 8;
    bf16x8 xa[2];
#pragma unroll
    for (int m = 0; m < 2; ++m) xa[m] = ld8(xrow + (16 * m + l15) * 256 + ko);
    bf16x8 fq = ld8(wq + (16 * wid + l15) * 256 + ko);
    bf16x8 fk = ld8(wk + (16 * wid + l15) * 256 + ko);
#pragma unroll
    for (int m = 0; m < 2; ++m) {
      aq[m] = MFMA16(xa[m], fq, aq[m]);
      ak[m] = MFMA16(xa[m], fk, ak[m]);
    }
    bf16x8 fv[4];
#pragma unroll
    for (int m = 0; m < 4; ++m) fv[m] = ld8(wv + (64 * wid + 16 * m + l15) * 256 + ko);
#pragma unroll
    for (int m = 0; m < 4; ++m)
#pragma unroll
      for (int n = 0; n < 2; ++n) av[m][n] = MFMA16(fv[m], xa[n], av[m][n]);
  }

  int o = 16 * wid + l15;
#pragma unroll
  for (int m = 0; m < 2; ++m)
#pragma unroll
    for (int r = 0; r < 4; ++r) {
      int pos = n0 + 16 * m + 4 * g + r;
      float pe = PE[o * 4096 + pos];
      Qt[((size_t)b * 4096 + pos) * 64 + o] = f2bf(aq[m][r] + bQ[o] + pe);
      Kt[((size_t)b * 4096 + pos) * 64 + o] = f2bf(ak[m][r] + bK[o] + pe);
    }
#pragma unroll
  for (int m = 0; m < 4; ++m) {
    int ov = 64 * wid + 16 * m + 4 * g;
#pragma unroll
    for (int r = 0; r < 4; ++r) {
      float bvv = bV[ov + r];
#pragma unroll
      for (int n = 0; n < 2; ++n) {
        int pos = n0 + 16 * n + l15;
        Vc[((size_t)b * 256 + ov + r) * 4096 + pos] = f2bf(av[m][n][r] + bvv);
      }
    }
  }
}

// ---- pass 1: column sums, 512 thr, grid 256 linear (b = id&3) -------------
__global__ __launch_bounds__(512) void k_colsum(const u16* __restrict__ Qt,
                                                const u16* __restrict__ Kt,
                                                float* __restrict__ rs) {
  __shared__ float ps[8][16];
  int b = blockIdx.x & 3, j0 = (blockIdx.x >> 2) * 64;
  int lane = threadIdx.x & 63, wid = threadIdx.x >> 6;  // wid in [0,8)
  int l15 = lane & 15, g = lane >> 4;
  int w4 = wid & 3, ihalf = wid >> 2;
  const u16* qb = Qt + (size_t)b * 262144;
  const u16* kb = Kt + (size_t)b * 262144;
  int j = j0 + 16 * w4 + l15;
  bf16x8 fk[2];
#pragma unroll
  for (int h = 0; h < 2; ++h) fk[h] = ld8(kb + j * 64 + h * 32 + 8 * g);
  float part = 0.f;
  for (int i0 = ihalf * 2048; i0 < ihalf * 2048 + 2048; i0 += 64) {
    f32x4 acc[4];
#pragma unroll
    for (int m = 0; m < 4; ++m) acc[m] = fz4();
#pragma unroll
    for (int m = 0; m < 4; ++m) {
      const u16* qr = qb + (i0 + 16 * m + l15) * 64;
      acc[m] = MFMA16(ld8(qr + 8 * g), fk[0], acc[m]);
      acc[m] = MFMA16(ld8(qr + 32 + 8 * g), fk[1], acc[m]);
    }
#pragma unroll
    for (int m = 0; m < 4; ++m)
#pragma unroll
      for (int r = 0; r < 4; ++r) part += __expf(acc[m][r] * 0.125f);
  }
  part += __shfl_xor(part, 16);
  part += __shfl_xor(part, 32);
  if (g == 0) ps[wid][l15] = part;
  __syncthreads();
  if (ihalf == 0 && g == 0)
    rs[b * 4096 + j] = 1.0f / (ps[w4][l15] + ps[w4 + 4][l15]);
}

// ---- pass 2: attention, 1024 thr, grid 512 linear (b = id&3, XCD-pin) -----
// 32-i blocks (was 64): 2 blocks/CU -> 32 waves/CU. 256-j steps. Wave w:
// S+exp for j-strip 16w; PV over channel strip 16w. Inner loop = R12 with
// the i-tile m-loop 4->2. P tile 16.9KB; launch_bounds(1024,8) -> VGPR<=64.
__global__ __launch_bounds__(1024, 8) void k_attn(
    const u16* __restrict__ Qt, const u16* __restrict__ Kt,
    const u16* __restrict__ Vc, const float* __restrict__ rs,
    u16* __restrict__ attT) {
  __shared__ u16 P[32][264];  // 256 j + pad (row 528 B, 33x16B)
  int b = blockIdx.x & 3, i0 = (blockIdx.x >> 2) * 32;
  int lane = threadIdx.x & 63, wid = threadIdx.x >> 6;  // wid in [0,16)
  int l15 = lane & 15, g = lane >> 4;
  const u16* qb = Qt + (size_t)b * 262144;
  const u16* kb = Kt + (size_t)b * 262144;
  const u16* vb = Vc + (size_t)b * 1048576;
  const float* rsb = rs + b * 4096;

  bf16x8 aq[2][2];  // block's Q rows (i = i0+16m+l15), held for all j
#pragma unroll
  for (int m = 0; m < 2; ++m)
#pragma unroll
    for (int h = 0; h < 2; ++h)
      aq[m][h] = ld8(qb + (i0 + 16 * m + l15) * 64 + h * 32 + 8 * g);

  f32x4 oacc[2];  // lane: i = i0+16m+4g+r, c = 16*wid+l15
#pragma unroll
  for (int m = 0; m < 2; ++m) oacc[m] = fz4();

  for (int j0 = 0; j0 < 4096; j0 += 256) {
    // S + exp for this wave's 16-j strip (j = j0 + 16*wid + l15)
    const u16* kr = kb + (size_t)(j0 + 16 * wid + l15) * 64;
    bf16x8 fk0 = ld8(kr + 8 * g);
    bf16x8 fk1 = ld8(kr + 32 + 8 * g);
    float rsc = rsb[j0 + 16 * wid + l15];
    f32x4 s[2];
#pragma unroll
    for (int m = 0; m < 2; ++m) {
      s[m] = fz4();
      s[m] = MFMA16(aq[m][0], fk0, s[m]);
      s[m] = MFMA16(aq[m][1], fk1, s[m]);
    }
#pragma unroll
    for (int m = 0; m < 2; ++m)
#pragma unroll
      for (int r = 0; r < 4; ++r)
        P[16 * m + 4 * g + r][16 * wid + l15] = f2bf(__expf(s[m][r] * 0.125f) * rsc);
    __syncthreads();
    // PV: A = P rows i (8 k-chunks of 32 j), B = V rows c (strip 16*wid)
#pragma unroll
    for (int h = 0; h < 8; ++h) {
      bf16x8 ap[2];
#pragma unroll
      for (int m = 0; m < 2; ++m) ap[m] = ld8(&P[16 * m + l15][h * 32 + 8 * g]);
      bf16x8 fv = ld8(vb + (size_t)(16 * wid + l15) * 4096 + j0 + h * 32 + 8 * g);
#pragma unroll
      for (int m = 0; m < 2; ++m) oacc[m] = MFMA16(ap[m], fv, oacc[m]);
    }
    __syncthreads();
  }
  int c = 16 * wid + l15;
#pragma unroll
  for (int m = 0; m < 2; ++m)
#pragma unroll
    for (int r = 0; r < 4; ++r) {
      int pos = i0 + 16 * m + 4 * g + r;
      attT[((size_t)b * 4096 + pos) * 256 + c] = f2bf(oacc[m][r]);
    }
}

// ---- fused MLP, 512 thr, grid 256 linear (b = id&3) -----------------------
__global__ __launch_bounds__(512) void k_mlp(
    const u16* __restrict__ attT, const u16* __restrict__ w1,
    const float* __restrict__ b1, const u16* __restrict__ w2,
    const float* __restrict__ b2, const float* __restrict__ x,
    float* __restrict__ out) {
  __shared__ u16 hdnS[64][264];
  int b = blockIdx.x & 3, n0 = (blockIdx.x >> 2) * 64;
  int lane = threadIdx.x & 63, wid = threadIdx.x >> 6;  // wid in [0,8)
  int l15 = lane & 15, g = lane >> 4;
  const u16* arow = attT + ((size_t)b * 4096 + n0) * 256;

  // stage 1: hdn = mish(att @ W1^T + b1) -> LDS; wave strip = 32 h-channels
  {
    f32x4 acc[4][2];
#pragma unroll
    for (int m = 0; m < 4; ++m)
#pragma unroll
      for (int n = 0; n < 2; ++n) acc[m][n] = fz4();
    for (int kk = 0; kk < 8; ++kk) {
      int ko = kk * 32 + 8 * g;
      bf16x8 am[4], bn[2];
#pragma unroll
      for (int m = 0; m < 4; ++m) am[m] = ld8(arow + (16 * m + l15) * 256 + ko);
#pragma unroll
      for (int n = 0; n < 2; ++n) bn[n] = ld8(w1 + (32 * wid + 16 * n + l15) * 256 + ko);
#pragma unroll
      for (int m = 0; m < 4; ++m)
#pragma unroll
        for (int n = 0; n < 2; ++n) acc[m][n] = MFMA16(am[m], bn[n], acc[m][n]);
    }
#pragma unroll
    for (int m = 0; m < 4; ++m)
#pragma unroll
      for (int n = 0; n < 2; ++n) {
        int hh = 32 * wid + 16 * n + l15;
        float bb = b1[hh];
#pragma unroll
        for (int r = 0; r < 4; ++r) {
          float v = acc[m][n][r] + bb;
          float sp = (v > 15.f) ? v : __logf(1.f + __expf(v));
          float e2 = __expf(-2.f * sp);
          float th = (1.f - e2) / (1.f + e2);
          hdnS[16 * m + 4 * g + r][hh] = f2bf(v * th);
        }
      }
  }
  __syncthreads();

  // stage 2: out = hdn @ W2^T + b2 + x; wave strip = 32 o-channels
  {
    f32x4 acc[2][4];
#pragma unroll
    for (int m = 0; m < 2; ++m)
#pragma unroll
      for (int n = 0; n < 4; ++n) acc[m][n] = fz4();
    for (int kk = 0; kk < 8; ++kk) {
      int ko = kk * 32 + 8 * g;
      bf16x8 am[2], bn[4];
#pragma unroll
      for (int m = 0; m < 2; ++m) am[m] = ld8(w2 + (32 * wid + 16 * m + l15) * 256 + ko);
#pragma unroll
      for (int n = 0; n < 4; ++n) bn[n] = ld8(&hdnS[16 * n + l15][ko]);
#pragma unroll
      for (int m = 0; m < 2; ++m)
#pragma unroll
        for (int n = 0; n < 4; ++n) acc[m][n] = MFMA16(am[m], bn[n], acc[m][n]);
    }
#pragma unroll
    for (int m = 0; m < 2; ++m)
#pragma unroll
      for (int r = 0; r < 4; ++r) {
        int o = 32 * wid + 16 * m + 4 * g + r;
        float bias = b2[o];
#pragma unroll
        for (int n = 0; n < 4; ++n) {
          int pos = n0 + 16 * n + l15;
          size_t idx = ((size_t)b * 256 + o) * 4096 + pos;
          out[idx] = acc[m][n][r] + bias + x[idx];
        }
      }
  }
}

// ---- workspace layout (bytes) ---------------------------------------------
#define WS_XT 0u          //  8,388,608  xT  [4][4096][256] bf16
#define WS_QT 8388608u    //  2,097,152  Qt  [4][4096][64]  bf16
#define WS_KT 10485760u   //  2,097,152  Kt  [4][4096][64]  bf16
#define WS_VC 12582912u   //  8,388,608  Vc  [4][256][4096] bf16
#define WS_ATT 20971520u  //  8,388,608  attT[4][4096][256] bf16
#define WS_RS 29360128u   //     65,536  rs  [4][4096]      fp32
#define WS_WQ 29425664u   //     32,768
#define WS_WK 29458432u   //     32,768
#define WS_WV 29491200u   //    131,072
#define WS_W1 29622272u   //    131,072
#define WS_W2 29753344u   //    131,072   (end: 29,884,416)

extern "C" void kernel_launch(void* const* d_in, const int* in_sizes, int n_in,
                              void* d_out, int out_size, void* d_ws, size_t ws_size,
                              hipStream_t stream) {
  (void)in_sizes; (void)n_in; (void)out_size; (void)ws_size;
  const float* x  = (const float*)d_in[0];
  const float* WQ = (const float*)d_in[1];
  const float* bQ = (const float*)d_in[2];
  const float* WK = (const float*)d_in[3];
  const float* bK = (const float*)d_in[4];
  const float* WV = (const float*)d_in[5];
  const float* bV = (const float*)d_in[6];
  const float* PE = (const float*)d_in[7];
  const float* W1 = (const float*)d_in[8];
  const float* b1 = (const float*)d_in[9];
  const float* W2 = (const float*)d_in[10];
  const float* b2 = (const float*)d_in[11];
  float* out = (float*)d_out;
  char* ws = (char*)d_ws;

  u16* xT   = (u16*)(ws + WS_XT);
  u16* Qt   = (u16*)(ws + WS_QT);
  u16* Kt   = (u16*)(ws + WS_KT);
  u16* Vc   = (u16*)(ws + WS_VC);
  u16* attT = (u16*)(ws + WS_ATT);
  float* rs = (float*)(ws + WS_RS);
  u16* wqB  = (u16*)(ws + WS_WQ);
  u16* wkB  = (u16*)(ws + WS_WK);
  u16* wvB  = (u16*)(ws + WS_WV);
  u16* w1B  = (u16*)(ws + WS_W1);
  u16* w2B  = (u16*)(ws + WS_W2);

  k_convert<<<896, 256, 0, stream>>>(WQ, WK, WV, W1, W2, wqB, wkB, wvB, w1B, w2B);
  k_transpose<<<dim3(64, 4, 4), 256, 0, stream>>>(x, xT);
  k_proj<<<512, 256, 0, stream>>>(xT, wqB, wkB, wvB, bQ, bK, bV, PE, Qt, Kt, Vc);
  k_colsum<<<256, 512, 0, stream>>>(Qt, Kt, rs);
  k_attn<<<512, 1024, 0, stream>>>(Qt, Kt, Vc, rs, attT);
  k_mlp<<<256, 512, 0, stream>>>(attT, w1B, b1, w2B, b2, x, out);
}

// Round 5
// 285.485 us; speedup vs baseline: 1.4918x; 1.2038x over previous
//
#include <hip/hip_runtime.h>

// ---------------------------------------------------------------------------
// AttentionHead: B=4, C=256, N=4096, QK=64. Column-softmax attention.
// R17 = R12 (the 284.8us best, verbatim) + ONE change: Vc row pitch padded
// 4096 -> 4352 u16 (+512B). Theory: k_attn's V gather reads 64B lines at
// exactly 8KB stride -> all lines of every V instruction (and all waves'
// streams) map to ONE L2 channel; per-XCD serialization at ~64B/cyc
// reproduces the measured 107us analytically (262K cyc). R13/R16 confirmed:
// 2x i-blocks => 2x V re-reads => ~2x time; occupancy 43->81% changed
// nothing. Padded pitch (8704B/row) rotates channel bits per row.
// attT aliases the dead xT slot so workspace stays 29,884,416 bytes.
// ---------------------------------------------------------------------------

typedef unsigned short u16;
typedef __attribute__((ext_vector_type(8))) unsigned short ushort8;
typedef __attribute__((ext_vector_type(8))) __bf16 bf16x8;
typedef __attribute__((ext_vector_type(4))) float f32x4;

#define MFMA16(a, b, c) __builtin_amdgcn_mfma_f32_16x16x32_bf16((a), (b), (c), 0, 0, 0)

#define VP 4352  // padded Vc row pitch in u16 (8704 B = 8192 + 512)

__device__ __forceinline__ u16 f2bf(float f) {
  unsigned int u = __builtin_bit_cast(unsigned int, f);
  u += 0x7FFFu + ((u >> 16) & 1u);  // round-to-nearest-even
  return (u16)(u >> 16);
}

__device__ __forceinline__ bf16x8 ld8(const u16* p) {
  return __builtin_bit_cast(bf16x8, *reinterpret_cast<const ushort8*>(p));
}

__device__ __forceinline__ f32x4 fz4() {
  f32x4 z = {0.f, 0.f, 0.f, 0.f};
  return z;
}

// ---- convert all weight matrices fp32 -> bf16 (one launch) ----------------
__global__ __launch_bounds__(256) void k_convert(
    const float* __restrict__ wq, const float* __restrict__ wk,
    const float* __restrict__ wv, const float* __restrict__ w1,
    const float* __restrict__ w2, u16* __restrict__ dq, u16* __restrict__ dk,
    u16* __restrict__ dv, u16* __restrict__ d1, u16* __restrict__ d2) {
  int i = blockIdx.x * 256 + threadIdx.x;
  if (i < 16384)       dq[i]           = f2bf(wq[i]);
  else if (i < 32768)  dk[i - 16384]   = f2bf(wk[i - 16384]);
  else if (i < 98304)  dv[i - 32768]   = f2bf(wv[i - 32768]);
  else if (i < 163840) d1[i - 98304]   = f2bf(w1[i - 98304]);
  else                 d2[i - 163840]  = f2bf(w2[i - 163840]);
}

// ---- x [b][256][4096] fp32 -> xT [b][4096][256] bf16 (LDS-tiled) ----------
__global__ __launch_bounds__(256) void k_transpose(const float* __restrict__ x,
                                                   u16* __restrict__ xT) {
  __shared__ float t[64][65];
  int n0 = blockIdx.x * 64, c0 = blockIdx.y * 64, b = blockIdx.z;
  int tx = threadIdx.x & 63, ty = threadIdx.x >> 6;
  const float* xb = x + ((size_t)b * 256 + c0) * 4096 + n0;
#pragma unroll
  for (int i = 0; i < 64; i += 4) t[ty + i][tx] = xb[(size_t)(ty + i) * 4096 + tx];
  __syncthreads();
  u16* xo = xT + ((size_t)b * 4096 + n0) * 256 + c0;
#pragma unroll
  for (int i = 0; i < 64; i += 4) xo[(size_t)(ty + i) * 256 + tx] = f2bf(t[tx][ty + i]);
}

// ---- fused QKV projection: 32-pos tiles, grid 512 linear (b = id&3) -------
__global__ __launch_bounds__(256) void k_proj(
    const u16* __restrict__ xT, const u16* __restrict__ wq,
    const u16* __restrict__ wk, const u16* __restrict__ wv,
    const float* __restrict__ bQ, const float* __restrict__ bK,
    const float* __restrict__ bV, const float* __restrict__ PE,
    u16* __restrict__ Qt, u16* __restrict__ Kt, u16* __restrict__ Vc) {
  int b = blockIdx.x & 3, n0 = (blockIdx.x >> 2) * 32;
  int lane = threadIdx.x & 63, wid = threadIdx.x >> 6;
  int l15 = lane & 15, g = lane >> 4;
  const u16* xrow = xT + ((size_t)b * 4096 + n0) * 256;

  f32x4 aq[2], ak[2], av[4][2];
#pragma unroll
  for (int m = 0; m < 2; ++m) { aq[m] = fz4(); ak[m] = fz4(); }
#pragma unroll
  for (int m = 0; m < 4; ++m)
#pragma unroll
    for (int n = 0; n < 2; ++n) av[m][n] = fz4();

  for (int kk = 0; kk < 8; ++kk) {
    int ko = kk * 32 + g * 8;
    bf16x8 xa[2];
#pragma unroll
    for (int m = 0; m < 2; ++m) xa[m] = ld8(xrow + (16 * m + l15) * 256 + ko);
    bf16x8 fq = ld8(wq + (16 * wid + l15) * 256 + ko);
    bf16x8 fk = ld8(wk + (16 * wid + l15) * 256 + ko);
#pragma unroll
    for (int m = 0; m < 2; ++m) {
      aq[m] = MFMA16(xa[m], fq, aq[m]);
      ak[m] = MFMA16(xa[m], fk, ak[m]);
    }
    bf16x8 fv[4];
#pragma unroll
    for (int m = 0; m < 4; ++m) fv[m] = ld8(wv + (64 * wid + 16 * m + l15) * 256 + ko);
#pragma unroll
    for (int m = 0; m < 4; ++m)
#pragma unroll
      for (int n = 0; n < 2; ++n) av[m][n] = MFMA16(fv[m], xa[n], av[m][n]);
  }

  int o = 16 * wid + l15;
#pragma unroll
  for (int m = 0; m < 2; ++m)
#pragma unroll
    for (int r = 0; r < 4; ++r) {
      int pos = n0 + 16 * m + 4 * g + r;
      float pe = PE[o * 4096 + pos];
      Qt[((size_t)b * 4096 + pos) * 64 + o] = f2bf(aq[m][r] + bQ[o] + pe);
      Kt[((size_t)b * 4096 + pos) * 64 + o] = f2bf(ak[m][r] + bK[o] + pe);
    }
#pragma unroll
  for (int m = 0; m < 4; ++m) {
    int ov = 64 * wid + 16 * m + 4 * g;
#pragma unroll
    for (int r = 0; r < 4; ++r) {
      float bvv = bV[ov + r];
#pragma unroll
      for (int n = 0; n < 2; ++n) {
        int pos = n0 + 16 * n + l15;
        Vc[((size_t)b * 256 + ov + r) * VP + pos] = f2bf(av[m][n][r] + bvv);
      }
    }
  }
}

// ---- pass 1: column sums, 512 thr, grid 256 linear (b = id&3) -------------
__global__ __launch_bounds__(512) void k_colsum(const u16* __restrict__ Qt,
                                                const u16* __restrict__ Kt,
                                                float* __restrict__ rs) {
  __shared__ float ps[8][16];
  int b = blockIdx.x & 3, j0 = (blockIdx.x >> 2) * 64;
  int lane = threadIdx.x & 63, wid = threadIdx.x >> 6;  // wid in [0,8)
  int l15 = lane & 15, g = lane >> 4;
  int w4 = wid & 3, ihalf = wid >> 2;
  const u16* qb = Qt + (size_t)b * 262144;
  const u16* kb = Kt + (size_t)b * 262144;
  int j = j0 + 16 * w4 + l15;
  bf16x8 fk[2];
#pragma unroll
  for (int h = 0; h < 2; ++h) fk[h] = ld8(kb + j * 64 + h * 32 + 8 * g);
  float part = 0.f;
  for (int i0 = ihalf * 2048; i0 < ihalf * 2048 + 2048; i0 += 64) {
    f32x4 acc[4];
#pragma unroll
    for (int m = 0; m < 4; ++m) acc[m] = fz4();
#pragma unroll
    for (int m = 0; m < 4; ++m) {
      const u16* qr = qb + (i0 + 16 * m + l15) * 64;
      acc[m] = MFMA16(ld8(qr + 8 * g), fk[0], acc[m]);
      acc[m] = MFMA16(ld8(qr + 32 + 8 * g), fk[1], acc[m]);
    }
#pragma unroll
    for (int m = 0; m < 4; ++m)
#pragma unroll
      for (int r = 0; r < 4; ++r) part += __expf(acc[m][r] * 0.125f);
  }
  part += __shfl_xor(part, 16);
  part += __shfl_xor(part, 32);
  if (g == 0) ps[wid][l15] = part;
  __syncthreads();
  if (ihalf == 0 && g == 0)
    rs[b * 4096 + j] = 1.0f / (ps[w4][l15] + ps[w4 + 4][l15]);
}

// ---- pass 2: attention, 1024 thr, grid 256 linear (b = id&3, XCD-pin) -----
// R12 body verbatim; only the Vc row pitch changed to VP (channel spread).
__global__ __launch_bounds__(1024) void k_attn(
    const u16* __restrict__ Qt, const u16* __restrict__ Kt,
    const u16* __restrict__ Vc, const float* __restrict__ rs,
    u16* __restrict__ attT) {
  __shared__ u16 P[64][264];  // 256 j + pad (row 528 B, 33x16B)
  int b = blockIdx.x & 3, i0 = (blockIdx.x >> 2) * 64;
  int lane = threadIdx.x & 63, wid = threadIdx.x >> 6;  // wid in [0,16)
  int l15 = lane & 15, g = lane >> 4;
  const u16* qb = Qt + (size_t)b * 262144;
  const u16* kb = Kt + (size_t)b * 262144;
  const u16* vb = Vc + (size_t)b * 256 * VP;
  const float* rsb = rs + b * 4096;

  bf16x8 aq[4][2];  // block's Q rows (i = i0+16m+l15), held for all j
#pragma unroll
  for (int m = 0; m < 4; ++m)
#pragma unroll
    for (int h = 0; h < 2; ++h)
      aq[m][h] = ld8(qb + (i0 + 16 * m + l15) * 64 + h * 32 + 8 * g);

  f32x4 oacc[4];  // lane: i = i0+16m+4g+r, c = 16*wid+l15
#pragma unroll
  for (int m = 0; m < 4; ++m) oacc[m] = fz4();

  for (int j0 = 0; j0 < 4096; j0 += 256) {
    // S + exp for this wave's 16-j strip (j = j0 + 16*wid + l15)
    const u16* kr = kb + (size_t)(j0 + 16 * wid + l15) * 64;
    bf16x8 fk0 = ld8(kr + 8 * g);
    bf16x8 fk1 = ld8(kr + 32 + 8 * g);
    float rsc = rsb[j0 + 16 * wid + l15];
    f32x4 s[4];
#pragma unroll
    for (int m = 0; m < 4; ++m) {
      s[m] = fz4();
      s[m] = MFMA16(aq[m][0], fk0, s[m]);
      s[m] = MFMA16(aq[m][1], fk1, s[m]);
    }
#pragma unroll
    for (int m = 0; m < 4; ++m)
#pragma unroll
      for (int r = 0; r < 4; ++r)
        P[16 * m + 4 * g + r][16 * wid + l15] = f2bf(__expf(s[m][r] * 0.125f) * rsc);
    __syncthreads();
    // PV: A = P rows i (8 k-chunks of 32 j), B = V rows c (strip 16*wid)
#pragma unroll
    for (int h = 0; h < 8; ++h) {
      bf16x8 ap[4];
#pragma unroll
      for (int m = 0; m < 4; ++m) ap[m] = ld8(&P[16 * m + l15][h * 32 + 8 * g]);
      bf16x8 fv = ld8(vb + (size_t)(16 * wid + l15) * VP + j0 + h * 32 + 8 * g);
#pragma unroll
      for (int m = 0; m < 4; ++m) oacc[m] = MFMA16(ap[m], fv, oacc[m]);
    }
    __syncthreads();
  }
  int c = 16 * wid + l15;
#pragma unroll
  for (int m = 0; m < 4; ++m)
#pragma unroll
    for (int r = 0; r < 4; ++r) {
      int pos = i0 + 16 * m + 4 * g + r;
      attT[((size_t)b * 4096 + pos) * 256 + c] = f2bf(oacc[m][r]);
    }
}

// ---- fused MLP, 512 thr, grid 256 linear (b = id&3) -----------------------
__global__ __launch_bounds__(512) void k_mlp(
    const u16* __restrict__ attT, const u16* __restrict__ w1,
    const float* __restrict__ b1, const u16* __restrict__ w2,
    const float* __restrict__ b2, const float* __restrict__ x,
    float* __restrict__ out) {
  __shared__ u16 hdnS[64][264];
  int b = blockIdx.x & 3, n0 = (blockIdx.x >> 2) * 64;
  int lane = threadIdx.x & 63, wid = threadIdx.x >> 6;  // wid in [0,8)
  int l15 = lane & 15, g = lane >> 4;
  const u16* arow = attT + ((size_t)b * 4096 + n0) * 256;

  // stage 1: hdn = mish(att @ W1^T + b1) -> LDS; wave strip = 32 h-channels
  {
    f32x4 acc[4][2];
#pragma unroll
    for (int m = 0; m < 4; ++m)
#pragma unroll
      for (int n = 0; n < 2; ++n) acc[m][n] = fz4();
    for (int kk = 0; kk < 8; ++kk) {
      int ko = kk * 32 + 8 * g;
      bf16x8 am[4], bn[2];
#pragma unroll
      for (int m = 0; m < 4; ++m) am[m] = ld8(arow + (16 * m + l15) * 256 + ko);
#pragma unroll
      for (int n = 0; n < 2; ++n) bn[n] = ld8(w1 + (32 * wid + 16 * n + l15) * 256 + ko);
#pragma unroll
      for (int m = 0; m < 4; ++m)
#pragma unroll
        for (int n = 0; n < 2; ++n) acc[m][n] = MFMA16(am[m], bn[n], acc[m][n]);
    }
#pragma unroll
    for (int m = 0; m < 4; ++m)
#pragma unroll
      for (int n = 0; n < 2; ++n) {
        int hh = 32 * wid + 16 * n + l15;
        float bb = b1[hh];
#pragma unroll
        for (int r = 0; r < 4; ++r) {
          float v = acc[m][n][r] + bb;
          float sp = (v > 15.f) ? v : __logf(1.f + __expf(v));
          float e2 = __expf(-2.f * sp);
          float th = (1.f - e2) / (1.f + e2);
          hdnS[16 * m + 4 * g + r][hh] = f2bf(v * th);
        }
      }
  }
  __syncthreads();

  // stage 2: out = hdn @ W2^T + b2 + x; wave strip = 32 o-channels
  {
    f32x4 acc[2][4];
#pragma unroll
    for (int m = 0; m < 2; ++m)
#pragma unroll
      for (int n = 0; n < 4; ++n) acc[m][n] = fz4();
    for (int kk = 0; kk < 8; ++kk) {
      int ko = kk * 32 + 8 * g;
      bf16x8 am[2], bn[4];
#pragma unroll
      for (int m = 0; m < 2; ++m) am[m] = ld8(w2 + (32 * wid + 16 * m + l15) * 256 + ko);
#pragma unroll
      for (int n = 0; n < 4; ++n) bn[n] = ld8(&hdnS[16 * n + l15][ko]);
#pragma unroll
      for (int m = 0; m < 2; ++m)
#pragma unroll
        for (int n = 0; n < 4; ++n) acc[m][n] = MFMA16(am[m], bn[n], acc[m][n]);
    }
#pragma unroll
    for (int m = 0; m < 2; ++m)
#pragma unroll
      for (int r = 0; r < 4; ++r) {
        int o = 32 * wid + 16 * m + 4 * g + r;
        float bias = b2[o];
#pragma unroll
        for (int n = 0; n < 4; ++n) {
          int pos = n0 + 16 * n + l15;
          size_t idx = ((size_t)b * 256 + o) * 4096 + pos;
          out[idx] = acc[m][n][r] + bias + x[idx];
        }
      }
  }
}

// ---- workspace layout (bytes) ---------------------------------------------
// attT aliases xT (xT dead after k_proj; attT written by k_attn, read k_mlp).
#define WS_XT 0u          //  8,388,608  xT  [4][4096][256] bf16  (= attT)
#define WS_ATT 0u         //  8,388,608  attT[4][4096][256] bf16  (= xT)
#define WS_QT 8388608u    //  2,097,152  Qt  [4][4096][64]  bf16
#define WS_KT 10485760u   //  2,097,152  Kt  [4][4096][64]  bf16
#define WS_VC 12582912u   //  8,912,896  Vc  [4][256][4352] bf16 (padded)
#define WS_RS 21495808u   //     65,536  rs  [4][4096]      fp32
#define WS_WQ 21561344u   //     32,768
#define WS_WK 21594112u   //     32,768
#define WS_WV 21626880u   //    131,072
#define WS_W1 21757952u   //    131,072
#define WS_W2 21889024u   //    131,072   (end: 22,020,096 < 29,884,416)

extern "C" void kernel_launch(void* const* d_in, const int* in_sizes, int n_in,
                              void* d_out, int out_size, void* d_ws, size_t ws_size,
                              hipStream_t stream) {
  (void)in_sizes; (void)n_in; (void)out_size; (void)ws_size;
  const float* x  = (const float*)d_in[0];
  const float* WQ = (const float*)d_in[1];
  const float* bQ = (const float*)d_in[2];
  const float* WK = (const float*)d_in[3];
  const float* bK = (const float*)d_in[4];
  const float* WV = (const float*)d_in[5];
  const float* bV = (const float*)d_in[6];
  const float* PE = (const float*)d_in[7];
  const float* W1 = (const float*)d_in[8];
  const float* b1 = (const float*)d_in[9];
  const float* W2 = (const float*)d_in[10];
  const float* b2 = (const float*)d_in[11];
  float* out = (float*)d_out;
  char* ws = (char*)d_ws;

  u16* xT   = (u16*)(ws + WS_XT);
  u16* Qt   = (u16*)(ws + WS_QT);
  u16* Kt   = (u16*)(ws + WS_KT);
  u16* Vc   = (u16*)(ws + WS_VC);
  u16* attT = (u16*)(ws + WS_ATT);
  float* rs = (float*)(ws + WS_RS);
  u16* wqB  = (u16*)(ws + WS_WQ);
  u16* wkB  = (u16*)(ws + WS_WK);
  u16* wvB  = (u16*)(ws + WS_WV);
  u16* w1B  = (u16*)(ws + WS_W1);
  u16* w2B  = (u16*)(ws + WS_W2);

  k_convert<<<896, 256, 0, stream>>>(WQ, WK, WV, W1, W2, wqB, wkB, wvB, w1B, w2B);
  k_transpose<<<dim3(64, 4, 4), 256, 0, stream>>>(x, xT);
  k_proj<<<512, 256, 0, stream>>>(xT, wqB, wkB, wvB, bQ, bK, bV, PE, Qt, Kt, Vc);
  k_colsum<<<256, 512, 0, stream>>>(Qt, Kt, rs);
  k_attn<<<256, 1024, 0, stream>>>(Qt, Kt, Vc, rs, attT);
  k_mlp<<<256, 512, 0, stream>>>(attT, w1B, b1, w2B, b2, x, out);
}